// Round 2
// baseline (1870.384 us; speedup 1.0000x reference)
//
#include <hip/hip_runtime.h>

// BitNet MLP: out = (silu(x@Gw^T * gs) * (x@Uw^T * us)) @ Dw^T * ds
// M=4096 tokens, K=4096 hidden, I=11008 inter. Ternary weights -> exact in bf16.
//
// R8: (a) register-fragment software pipeline: each K-tile body issues the
// next phase's ds_reads BEFORE running the current MFMA cluster, so LDS reads
// overlap MFMA (R7's strict read->wait->MFMA alternation capped MfmaUtil at
// 45% = 310cy MFMA / (410cy reads + 280cy MFMA) per K-tile).
// (b) fused dequant staging: B weights are read as f32 inside the GEMM and
// truncated to bf16 (exact for ternary: low 16 bits of +-1.0/0.0 are zero)
// during reg->LDS staging. Eliminates the cvt2/cvt-down kernels (~200us) and
// the bf16 weight workspace round-trip. A-side keeps global_load_lds.
// LDS: A 3x16KB + B 3x16KB = 96KB. B frag sets double-buffered with static
// names (loop unrolled x2). vmcnt never drains to 0 in the main loop (VMW(2):
// the current body's 2 A-glds stay in flight across the barrier).

typedef short short8 __attribute__((ext_vector_type(8)));
typedef float f32x4 __attribute__((ext_vector_type(4)));
typedef float fvec4 __attribute__((ext_vector_type(4)));
typedef unsigned short usvec4 __attribute__((ext_vector_type(4)));
typedef unsigned int u32x4 __attribute__((ext_vector_type(4)));
typedef unsigned int u32x2 __attribute__((ext_vector_type(2)));

__device__ __forceinline__ unsigned short f2bf(float f) {
    unsigned int u = __float_as_uint(f);
    u += 0x7FFFu + ((u >> 16) & 1u);   // round-to-nearest-even
    return (unsigned short)(u >> 16);
}

__global__ void cvt_f32_bf16(const fvec4* __restrict__ src,
                             usvec4* __restrict__ dst, long n4) {
    long i = (long)blockIdx.x * blockDim.x + threadIdx.x;
    if (i < n4) {
        fvec4 v = __builtin_nontemporal_load(src + i);
        usvec4 o;
        o.x = f2bf(v.x); o.y = f2bf(v.y); o.z = f2bf(v.z); o.w = f2bf(v.w);
        dst[i] = o;
    }
}

#define GLOBAL_TO_LDS(gp, lp)                                                  \
    __builtin_amdgcn_global_load_lds(                                          \
        (__attribute__((address_space(1))) const void*)(gp),                   \
        (__attribute__((address_space(3))) void*)(lp), 16, 0, 0)

#define BAR() __builtin_amdgcn_s_barrier()
#define SCHEDB() __builtin_amdgcn_sched_barrier(0)
#define LGKM0() do { asm volatile("s_waitcnt lgkmcnt(0)" ::: "memory"); SCHEDB(); } while (0)
#define VMW_(n) asm volatile("s_waitcnt vmcnt(" #n ")" ::: "memory")
#define VMW(n) VMW_(n)

// bijective XCD-aware block remap (m204). gridDim.x == 16 always here.
__device__ __forceinline__ void remap_block(int gy, int& bx, int& by) {
    int nwg = gy << 4;
    int orig = blockIdx.y * 16 + blockIdx.x;
    int q = nwg >> 3, r = nwg & 7;
    int xcd = orig & 7, lid = orig >> 3;
    int wg = (xcd < r ? xcd * (q + 1) : r * (q + 1) + (xcd - r) * q) + lid;
    bx = wg & 15;
    by = wg >> 4;
}

// Shared K-tile body. Expects in scope: lds, qr,qs,br,bw, aoff,boff, t,
// ah0[4],ah1[4],acc[8][4], wreg[4], pb[4] (const float*), pa0,pa1, wds.
// Phase overlap: tile kt's 8 ds_reads are in flight during tile kt-1's h1
// MFMA; tile kt's h1 ds_reads are in flight during its h0 MFMA.
#define KBODY(BC, BP, DO_PREV, DO_SA, DO_SB, VMTOK, DO_WR)                    \
  do {                                                                        \
    BAR();                                                                    \
    if (DO_SB) {                                                              \
      _Pragma("unroll") for (int j = 0; j < 4; ++j) {                         \
        wreg[j] = *(const u32x4*)pb[j];                                       \
        pb[j] += 32;                                                          \
      }                                                                       \
    }                                                                         \
    {                                                                         \
      const unsigned short* Aq = lds + qr * 8192;                             \
      const unsigned short* Bq = lds + 24576 + br * 8192;                     \
      _Pragma("unroll") for (int i = 0; i < 4; ++i)                           \
        ah0[i] = *(const short8*)(Aq + aoff + i * 512);                       \
      _Pragma("unroll") for (int n = 0; n < 4; ++n)                           \
        BC[n] = *(const short8*)(Bq + boff + n * 512);                        \
      SCHEDB();                                                               \
      if (DO_PREV) {                                                          \
        __builtin_amdgcn_s_setprio(1);                                        \
        _Pragma("unroll") for (int mi = 0; mi < 4; ++mi)                      \
          _Pragma("unroll") for (int ni = 0; ni < 4; ++ni)                    \
            acc[4 + mi][ni] = __builtin_amdgcn_mfma_f32_16x16x32_bf16(        \
                ah1[mi], BP[ni], acc[4 + mi][ni], 0, 0, 0);                   \
        __builtin_amdgcn_s_setprio(0);                                        \
      }                                                                       \
      SCHEDB();                                                               \
      if (DO_SA) {                                                            \
        unsigned short* As = lds + qs * 8192;                                 \
        GLOBAL_TO_LDS(pa0, As + t * 8);                                       \
        GLOBAL_TO_LDS(pa1, As + 4096 + t * 8);                                \
        pa0 += 32; pa1 += 32;                                                 \
      }                                                                       \
      SCHEDB();                                                               \
      LGKM0();                                                                \
      _Pragma("unroll") for (int i = 0; i < 4; ++i)                           \
        ah1[i] = *(const short8*)(Aq + aoff + (4 + i) * 512);                 \
      SCHEDB();                                                               \
      __builtin_amdgcn_s_setprio(1);                                          \
      _Pragma("unroll") for (int mi = 0; mi < 4; ++mi)                        \
        _Pragma("unroll") for (int ni = 0; ni < 4; ++ni)                      \
          acc[mi][ni] = __builtin_amdgcn_mfma_f32_16x16x32_bf16(              \
              ah0[mi], BC[ni], acc[mi][ni], 0, 0, 0);                         \
      __builtin_amdgcn_s_setprio(0);                                          \
      SCHEDB();                                                               \
      VMW(VMTOK);                                                             \
      if (DO_WR) {                                                            \
        unsigned short* Bw = lds + 24576 + bw * 8192;                         \
        _Pragma("unroll") for (int j = 0; j < 4; ++j) {                       \
          unsigned u0 = (wreg[j].x >> 16) | (wreg[j].y & 0xFFFF0000u);        \
          unsigned u1 = (wreg[j].z >> 16) | (wreg[j].w & 0xFFFF0000u);        \
          *(u32x2*)(Bw + j * 2048 + wds) = (u32x2){u0, u1};                   \
        }                                                                     \
      }                                                                       \
      LGKM0();                                                                \
    }                                                                         \
    qr = qr == 2 ? 0 : qr + 1;                                                \
    qs = qs == 2 ? 0 : qs + 1;                                                \
    br = br == 2 ? 0 : br + 1;                                                \
    bw = bw == 2 ? 0 : bw + 1;                                                \
  } while (0)

// Prologue: issue B0 regs + A0/A1 glds; truncate-convert and write B0.
#define KPROLOGUE()                                                           \
  do {                                                                        \
    _Pragma("unroll") for (int j = 0; j < 4; ++j) {                           \
      wreg[j] = *(const u32x4*)pb[j];                                         \
      pb[j] += 32;                                                            \
    }                                                                         \
    GLOBAL_TO_LDS(pa0, lds + t * 8);                                          \
    GLOBAL_TO_LDS(pa1, lds + 4096 + t * 8);                                   \
    pa0 += 32; pa1 += 32;                                                     \
    GLOBAL_TO_LDS(pa0, lds + 8192 + t * 8);                                   \
    GLOBAL_TO_LDS(pa1, lds + 8192 + 4096 + t * 8);                            \
    pa0 += 32; pa1 += 32;                                                     \
    VMW(4); /* B0 regs done; A0,A1 in flight */                               \
    {                                                                         \
      unsigned short* Bw = lds + 24576;                                       \
      _Pragma("unroll") for (int j = 0; j < 4; ++j) {                         \
        unsigned u0 = (wreg[j].x >> 16) | (wreg[j].y & 0xFFFF0000u);          \
        unsigned u1 = (wreg[j].z >> 16) | (wreg[j].w & 0xFFFF0000u);          \
        *(u32x2*)(Bw + j * 2048 + wds) = (u32x2){u0, u1};                     \
      }                                                                       \
    }                                                                         \
    VMW(2); /* A0 done; A1 in flight */                                       \
    LGKM0();                                                                  \
  } while (0)

#define KLOOP()                                                               \
  do {                                                                        \
    KBODY(bF0, bF1, 0, 1, 1, 2, 1); /* kt=0 */                                \
    KBODY(bF1, bF0, 1, 1, 1, 2, 1); /* kt=1 */                                \
    for (int kt = 2; kt < Kt - 2; kt += 2) {                                  \
      KBODY(bF0, bF1, 1, 1, 1, 2, 1);                                         \
      KBODY(bF1, bF0, 1, 1, 1, 2, 1);                                         \
    }                                                                         \
    KBODY(bF0, bF1, 1, 0, 1, 0, 1); /* kt=Kt-2: no A stage, drain */          \
    KBODY(bF1, bF0, 1, 0, 0, 0, 0); /* kt=Kt-1: no stages */                  \
    __builtin_amdgcn_s_setprio(1);                                            \
    _Pragma("unroll") for (int mi = 0; mi < 4; ++mi)                          \
      _Pragma("unroll") for (int ni = 0; ni < 4; ++ni)                        \
        acc[4 + mi][ni] = __builtin_amdgcn_mfma_f32_16x16x32_bf16(            \
            ah1[mi], bF1[ni], acc[4 + mi][ni], 0, 0, 0);                      \
    __builtin_amdgcn_s_setprio(0);                                            \
  } while (0)

// ---------------------------------------------------------------------------
// gemm1: X[4096 x K] @ [Gw;Uw interleaved by 16-row groups]^T, SwiGLU -> inter
// 256(M) x 256(combined N) tile, 8 waves (2M x 4N), BK=32. Weights read f32.
// ---------------------------------------------------------------------------
__global__ __launch_bounds__(512, 2)
void gemm1_swiglu(const unsigned short* __restrict__ Xb,
                  const float* __restrict__ Gw,
                  const float* __restrict__ Uw,
                  unsigned short* __restrict__ inter,
                  const float* __restrict__ gs_p,
                  const float* __restrict__ us_p,
                  int K, int I, int gy) {
    extern __shared__ unsigned short lds[];   // A: [0,24576) B: [24576,49152)

    int bx, by;
    remap_block(gy, bx, by);

    const int t = threadIdx.x;
    const int lane = t & 63;
    const int wid = t >> 6;
    const int wm = (wid >> 2) * 128;
    const int wn = (wid & 3) * 64;
    const int fr = lane & 15;
    const int ca = (((lane >> 4) ^ ((fr >> 1) & 3)) << 3);

    const int m_base = bx * 256;

    // A staging (bf16 src, pre-swizzled column, linear LDS dest)
    const int colsw = (((t & 3) ^ ((t >> 3) & 3)) << 3);
    const unsigned short* pa0 = Xb + (size_t)(m_base + (t >> 2)) * K + colsw;
    const unsigned short* pa1 = pa0 + (size_t)128 * K;

    // B reg staging: 4 rows/thread (64 apart), 4 f32 each (8-lane 128B bursts)
    const float* pb[4];
#pragma unroll
    for (int j = 0; j < 4; ++j) {
        int rl = 64 * j + (t >> 3);
        int cg = by * 256 + rl;                       // combined row
        const float* base = ((cg >> 4) & 1) ? Uw : Gw;
        int srow = ((cg >> 5) << 4) + (cg & 15);      // source inter row
        pb[j] = base + (size_t)srow * K + 4 * (t & 7);
    }
    // ds_write offset (ushort units), swizzle matches read-side XOR
    const int tt = t >> 3;
    const int pg = ((t >> 1) & 3) ^ ((tt >> 1) & 3);
    const int wds = tt * 32 + pg * 8 + (t & 1) * 4;

    f32x4 acc[8][4];
    const f32x4 z = {0.0f, 0.0f, 0.0f, 0.0f};
#pragma unroll
    for (int i = 0; i < 8; ++i)
#pragma unroll
        for (int j = 0; j < 4; ++j) acc[i][j] = z;

    const int aoff = (wm + fr) * 32 + ca;
    const int boff = (wn + fr) * 32 + ca;
    const int Kt = K >> 5;   // 128

    short8 ah0[4], ah1[4], bF0[4], bF1[4];
    u32x4 wreg[4];
    int qr = 0, qs = 2, br = 0, bw = 1;

    KPROLOGUE();
    KLOOP();

    // ---- SwiGLU epilogue: even 16-frag = gate, odd = up ----
    const float gsc = *gs_p;
    const float usc = *us_p;
    const int row0 = m_base + wm + ((lane >> 4) << 2);
    const int col0 = by * 128 + (wn >> 1) + fr;
#pragma unroll
    for (int mi = 0; mi < 8; ++mi)
#pragma unroll
        for (int p = 0; p < 2; ++p)
#pragma unroll
            for (int r = 0; r < 4; ++r) {
                float g = acc[mi][2 * p][r] * gsc;
                float u = acc[mi][2 * p + 1][r] * usc;
                float s = g / (1.0f + __expf(-g));   // silu
                inter[(size_t)(row0 + mi * 16 + r) * I + (col0 + p * 16)] =
                    f2bf(s * u);
            }
}

// ---------------------------------------------------------------------------
// gemm2: inter[4096 x I] @ Dw[H x I]^T * ds -> out f32. Same pipeline.
// ---------------------------------------------------------------------------
__global__ __launch_bounds__(512, 2)
void gemm2_down(const unsigned short* __restrict__ Ab,
                const float* __restrict__ Dw,
                float* __restrict__ out,
                const float* __restrict__ ds_p,
                int K, int H, int gy) {
    extern __shared__ unsigned short lds[];

    int bx, by;
    remap_block(gy, bx, by);

    const int t = threadIdx.x;
    const int lane = t & 63;
    const int wid = t >> 6;
    const int wm = (wid >> 2) * 128;
    const int wn = (wid & 3) * 64;
    const int fr = lane & 15;
    const int ca = (((lane >> 4) ^ ((fr >> 1) & 3)) << 3);

    const int m_base = bx * 256;

    const int colsw = (((t & 3) ^ ((t >> 3) & 3)) << 3);
    const unsigned short* pa0 = Ab + (size_t)(m_base + (t >> 2)) * K + colsw;
    const unsigned short* pa1 = pa0 + (size_t)128 * K;

    const float* pb[4];
#pragma unroll
    for (int j = 0; j < 4; ++j) {
        int rl = 64 * j + (t >> 3);
        pb[j] = Dw + (size_t)(by * 256 + rl) * K + 4 * (t & 7);
    }
    const int tt = t >> 3;
    const int pg = ((t >> 1) & 3) ^ ((tt >> 1) & 3);
    const int wds = tt * 32 + pg * 8 + (t & 1) * 4;

    f32x4 acc[8][4];
    const f32x4 z = {0.0f, 0.0f, 0.0f, 0.0f};
#pragma unroll
    for (int i = 0; i < 8; ++i)
#pragma unroll
        for (int j = 0; j < 4; ++j) acc[i][j] = z;

    const int aoff = (wm + fr) * 32 + ca;
    const int boff = (wn + fr) * 32 + ca;
    const int Kt = K >> 5;   // 344

    short8 ah0[4], ah1[4], bF0[4], bF1[4];
    u32x4 wreg[4];
    int qr = 0, qs = 2, br = 0, bw = 1;

    KPROLOGUE();
    KLOOP();

    const float dsc = *ds_p;
    const int row0 = m_base + wm + ((lane >> 4) << 2);
    const int col0 = by * 256 + wn + fr;
#pragma unroll
    for (int mi = 0; mi < 8; ++mi)
#pragma unroll
        for (int ni = 0; ni < 4; ++ni)
#pragma unroll
            for (int r = 0; r < 4; ++r)
                out[(size_t)(row0 + mi * 16 + r) * H + (col0 + ni * 16)] =
                    acc[mi][ni][r] * dsc;
}

extern "C" void kernel_launch(void* const* d_in, const int* in_sizes, int n_in,
                              void* d_out, int out_size, void* d_ws, size_t ws_size,
                              hipStream_t stream) {
    (void)in_sizes; (void)n_in; (void)out_size;
    const float* x  = (const float*)d_in[0];
    const float* gw = (const float*)d_in[1];
    const float* uw = (const float*)d_in[2];
    const float* dw = (const float*)d_in[3];
    const float* gs = (const float*)d_in[4];
    const float* us = (const float*)d_in[5];
    const float* ds = (const float*)d_in[6];
    float* out = (float*)d_out;

    const long M = 4096;    // BATCH*SEQ
    const long Kh = 4096;   // HIDDEN
    const long I = 11008;   // INTER
    const long H = 4096;

    (void)hipFuncSetAttribute(reinterpret_cast<const void*>(gemm1_swiglu),
                              hipFuncAttributeMaxDynamicSharedMemorySize, 98304);
    (void)hipFuncSetAttribute(reinterpret_cast<const void*>(gemm2_down),
                              hipFuncAttributeMaxDynamicSharedMemorySize, 98304);

    char* ws = (char*)d_ws;
    unsigned short* Xb = (unsigned short*)ws;                       // M*Kh bf16
    unsigned short* inter = (unsigned short*)(ws + M * Kh * 2);     // M*I bf16
    const size_t used = (size_t)M * Kh * 2 + (size_t)M * I * 2;     // ~124 MB
    if (ws_size < used) return;

    // ---- x -> bf16 (RNE; x is the only non-exact input) ----
    {
        long n4 = M * Kh / 4;
        cvt_f32_bf16<<<dim3((unsigned)((n4 + 255) / 256)), dim3(256), 0, stream>>>(
            (const fvec4*)x, (usvec4*)Xb, n4);
    }

    // ---- gemm1: single launch, weights dequantized in-kernel ----
    // combined N = 2*I = 22016 -> 86 tiles of 256
    gemm1_swiglu<<<dim3(16, 86), dim3(512), 98304, stream>>>(
        Xb, gw, uw, inter, gs, us, (int)Kh, (int)I, 86);

    // ---- gemm2: single launch ----
    gemm2_down<<<dim3(16, 16), dim3(512), 98304, stream>>>(
        inter, dw, out, ds, (int)I, (int)H, 16);
}

// Round 3
// 1394.421 us; speedup vs baseline: 1.3413x; 1.3413x over previous
//
#include <hip/hip_runtime.h>

// BitNet MLP: out = (silu(x@Gw^T * gs) * (x@Uw^T * us)) @ Dw^T * ds
// M=4096 tokens, K=4096 hidden, I=11008 inter. Ternary weights -> exact in bf16.
//
// R9: revert to R7 skeleton (glds A+B staging, cvt kernels, 4-deep LDS bufs,
// counted vmcnt) -- R8's fused-dequant regressed because its mixed vmcnt
// stream put B's HBM latency on the critical path. New: cross-tile software
// pipeline with ONE barrier per K-tile and partial lgkm waits so ds_read
// returns overlap MFMA issue:
//   top: lgkm(4) [ah0,bf(kt) done; ah1(kt) flies] -> h0-MFMA covers ah1
//   vmcnt(4)+BAR -> read ah0,bf(kt+1) + 4 glds->buf(kt+3)
//   lgkm(8) [ah1(kt) done; 8 new reads fly] -> h1-MFMA covers them
//   read ah1(kt+1)
// Only bf needs register double-buffering (bfA/bfB, x2-unrolled loop);
// ah0/ah1 reuse is WAR-safe in-order. vmcnt never drains until the last
// 2 iters. R7's verified swizzle/staging/epilogues unchanged.

typedef short short8 __attribute__((ext_vector_type(8)));
typedef float f32x4 __attribute__((ext_vector_type(4)));
typedef float fvec4 __attribute__((ext_vector_type(4)));
typedef unsigned short usvec4 __attribute__((ext_vector_type(4)));

__device__ __forceinline__ unsigned short f2bf(float f) {
    unsigned int u = __float_as_uint(f);
    u += 0x7FFFu + ((u >> 16) & 1u);   // round-to-nearest-even
    return (unsigned short)(u >> 16);
}

__global__ void cvt_f32_bf16(const fvec4* __restrict__ src,
                             usvec4* __restrict__ dst, long n4) {
    long i = (long)blockIdx.x * blockDim.x + threadIdx.x;
    if (i < n4) {
        fvec4 v = __builtin_nontemporal_load(src + i);
        usvec4 o;
        o.x = f2bf(v.x); o.y = f2bf(v.y); o.z = f2bf(v.z); o.w = f2bf(v.w);
        dst[i] = o;
    }
}

// Convert gate+up and interleave at 16-row granularity into one combined
// weight matrix: combined rows [32b..32b+16) = gate rows [16b..16b+16),
// combined rows [32b+16..32b+32) = up rows. Kh/4 == 1024 vec4 per row.
__global__ void cvt2_f32_bf16_ilv(const fvec4* __restrict__ s0,
                                  const fvec4* __restrict__ s1,
                                  usvec4* __restrict__ d, long n4) {
    long i = (long)blockIdx.x * blockDim.x + threadIdx.x;
    if (i < n4) {
        long j = i >> 10;          // local inter row
        long c = i & 1023;
        long Rg = ((j & ~15L) << 1) | (j & 15);
        fvec4 a = __builtin_nontemporal_load(s0 + i);
        fvec4 b = __builtin_nontemporal_load(s1 + i);
        usvec4 oa, ob;
        oa.x = f2bf(a.x); oa.y = f2bf(a.y); oa.z = f2bf(a.z); oa.w = f2bf(a.w);
        ob.x = f2bf(b.x); ob.y = f2bf(b.y); ob.z = f2bf(b.z); ob.w = f2bf(b.w);
        d[Rg * 1024 + c] = oa;
        d[(Rg + 16) * 1024 + c] = ob;
    }
}

#define GLOBAL_TO_LDS(gp, lp)                                                  \
    __builtin_amdgcn_global_load_lds(                                          \
        (__attribute__((address_space(1))) const void*)(gp),                   \
        (__attribute__((address_space(3))) void*)(lp), 16, 0, 0)

#define BAR() __builtin_amdgcn_s_barrier()
#define SCHEDB() __builtin_amdgcn_sched_barrier(0)
#define LGKM(n) do { asm volatile("s_waitcnt lgkmcnt(" #n ")" ::: "memory"); SCHEDB(); } while (0)
#define VMW(n) asm volatile("s_waitcnt vmcnt(" #n ")" ::: "memory")

// bijective XCD-aware block remap (m204). gridDim.x == 16 always here.
__device__ __forceinline__ void remap_block(int gy, int& bx, int& by) {
    int nwg = gy << 4;
    int orig = blockIdx.y * 16 + blockIdx.x;
    int q = nwg >> 3, r = nwg & 7;
    int xcd = orig & 7, lid = orig >> 3;
    int wg = (xcd < r ? xcd * (q + 1) : r * (q + 1) + (xcd - r) * q) + lid;
    bx = wg & 15;
    by = wg >> 4;
}

// One K-tile iteration of the pipelined loop. In scope: lds, t, aoff, boff,
// ah0[4], ah1[4], bfA[4], bfB[4], acc[8][4], pa0, pa1, pb0, pb1, Kt.
// BFC = current tile's B frags, BFN = next tile's (double-buffered).
// TOK4: vmcnt token (1 -> 4, 0 -> 0). PF_: stage buf kt+3. RA_: read tile kt+1.
#define KITER(KT_, BFC, BFN, TOK4, PF_, RA_)                                   \
  do {                                                                         \
    LGKM(4); /* ah0,BFC of kt done; ah1(kt) in flight */                       \
    __builtin_amdgcn_s_setprio(1);                                             \
    _Pragma("unroll") for (int mi = 0; mi < 4; ++mi)                           \
      _Pragma("unroll") for (int ni = 0; ni < 4; ++ni)                         \
        acc[mi][ni] = __builtin_amdgcn_mfma_f32_16x16x32_bf16(                 \
            ah0[mi], BFC[ni], acc[mi][ni], 0, 0, 0);                           \
    __builtin_amdgcn_s_setprio(0);                                             \
    SCHEDB();                                                                  \
    if (TOK4) { VMW(4); } else { VMW(0); }                                     \
    BAR(); /* buf kt+1 ready for all waves */                                  \
    if (RA_) {                                                                 \
      const unsigned short* Aq = lds + ((((KT_) + 1) & 3) << 13);              \
      const unsigned short* Bq = lds + 32768 + ((((KT_) + 1) & 3) << 13);      \
      _Pragma("unroll") for (int i = 0; i < 4; ++i)                            \
        ah0[i] = *(const short8*)(Aq + aoff + i * 512);                        \
      _Pragma("unroll") for (int n = 0; n < 4; ++n)                            \
        BFN[n] = *(const short8*)(Bq + boff + n * 512);                        \
    }                                                                          \
    if (PF_) {                                                                 \
      unsigned short* Aw = lds + ((((KT_) + 3) & 3) << 13);                    \
      unsigned short* Bw = lds + 32768 + ((((KT_) + 3) & 3) << 13);            \
      GLOBAL_TO_LDS(pa0, Aw + t * 8);                                          \
      GLOBAL_TO_LDS(pa1, Aw + 4096 + t * 8);                                   \
      GLOBAL_TO_LDS(pb0, Bw + t * 8);                                          \
      GLOBAL_TO_LDS(pb1, Bw + 4096 + t * 8);                                   \
      pa0 += 32; pa1 += 32; pb0 += 32; pb1 += 32;                              \
    }                                                                          \
    SCHEDB();                                                                  \
    if (RA_) { LGKM(8); } else { LGKM(0); } /* ah1(kt) done; new reads fly */  \
    __builtin_amdgcn_s_setprio(1);                                             \
    _Pragma("unroll") for (int mi = 0; mi < 4; ++mi)                           \
      _Pragma("unroll") for (int ni = 0; ni < 4; ++ni)                         \
        acc[4 + mi][ni] = __builtin_amdgcn_mfma_f32_16x16x32_bf16(             \
            ah1[mi], BFC[ni], acc[4 + mi][ni], 0, 0, 0);                       \
    __builtin_amdgcn_s_setprio(0);                                             \
    SCHEDB();                                                                  \
    if (RA_) { /* ah1(kt+1): returns covered by next iter's h0-MFMA */         \
      const unsigned short* Aq = lds + ((((KT_) + 1) & 3) << 13);              \
      _Pragma("unroll") for (int i = 0; i < 4; ++i)                            \
        ah1[i] = *(const short8*)(Aq + aoff + (4 + i) * 512);                  \
      SCHEDB();                                                                \
    }                                                                          \
  } while (0)

// Prologue: stage tiles 0,1,2 into bufs 0,1,2; read tile-0 frags.
#define KPRO()                                                                 \
  do {                                                                         \
    _Pragma("unroll") for (int s = 0; s < 3; ++s) {                            \
      unsigned short* Aw = lds + (s << 13);                                    \
      unsigned short* Bw = lds + 32768 + (s << 13);                            \
      GLOBAL_TO_LDS(pa0, Aw + t * 8);                                          \
      GLOBAL_TO_LDS(pa1, Aw + 4096 + t * 8);                                   \
      GLOBAL_TO_LDS(pb0, Bw + t * 8);                                          \
      GLOBAL_TO_LDS(pb1, Bw + 4096 + t * 8);                                   \
      pa0 += 32; pa1 += 32; pb0 += 32; pb1 += 32;                              \
    }                                                                          \
    VMW(8); BAR(); /* tile 0 landed; tiles 1,2 in flight */                    \
    _Pragma("unroll") for (int i = 0; i < 4; ++i)                              \
      ah0[i] = *(const short8*)(lds + aoff + i * 512);                         \
    _Pragma("unroll") for (int n = 0; n < 4; ++n)                              \
      bfA[n] = *(const short8*)(lds + 32768 + boff + n * 512);                 \
    _Pragma("unroll") for (int i = 0; i < 4; ++i)                              \
      ah1[i] = *(const short8*)(lds + aoff + (4 + i) * 512);                   \
    SCHEDB();                                                                  \
  } while (0)

// Main loop: Kt even, Kt >= 8. One barrier per K-tile; vmcnt(4) steady,
// drains only in the last 2 iters.
#define KLOOP()                                                                \
  do {                                                                         \
    for (int kt = 0; kt < Kt - 4; kt += 2) {                                   \
      KITER(kt, bfA, bfB, 1, 1, 1);                                            \
      KITER(kt + 1, bfB, bfA, 1, 1, 1);                                        \
    }                                                                          \
    KITER(Kt - 4, bfA, bfB, 1, 1, 1);                                          \
    KITER(Kt - 3, bfB, bfA, 1, 0, 1);                                          \
    KITER(Kt - 2, bfA, bfB, 0, 0, 1);                                          \
    KITER(Kt - 1, bfB, bfA, 0, 0, 0);                                          \
  } while (0)

// ---------------------------------------------------------------------------
// gemm1: X[4096 x K] @ [Gw;Uw interleaved]^T, SwiGLU epilogue -> inter bf16
// 256(M) x 256(combined N) tile, 8 waves (2M x 4N), BK=32, 4-deep bufs.
// ---------------------------------------------------------------------------
__global__ __launch_bounds__(512, 2)
void gemm1_swiglu(const unsigned short* __restrict__ Xb,
                  const unsigned short* __restrict__ Wc,
                  unsigned short* __restrict__ inter,
                  const float* __restrict__ gs_p,
                  const float* __restrict__ us_p,
                  int K, int I, int n0, int gy) {
    extern __shared__ unsigned short lds[];  // A: 4x8192 shorts, B: +32768

    int bx, by;
    remap_block(gy, bx, by);

    const int t = threadIdx.x;
    const int lane = t & 63;
    const int wid = t >> 6;
    const int wm = (wid >> 2) * 128;
    const int wn = (wid & 3) * 64;
    const int fr = lane & 15;
    const int ca = (((lane >> 4) ^ ((fr >> 1) & 3)) << 3);

    const int m_base = bx * 256;
    const long b_row0 = (long)by * 256;

    const int colsw = (((t & 3) ^ ((t >> 3) & 3)) << 3);
    const unsigned short* pa0 = Xb + (size_t)(m_base + (t >> 2)) * K + colsw;
    const unsigned short* pa1 = pa0 + (size_t)128 * K;
    const unsigned short* pb0 = Wc + (size_t)(b_row0 + (t >> 2)) * K + colsw;
    const unsigned short* pb1 = pb0 + (size_t)128 * K;

    f32x4 acc[8][4];
    const f32x4 z = {0.0f, 0.0f, 0.0f, 0.0f};
#pragma unroll
    for (int i = 0; i < 8; ++i)
#pragma unroll
        for (int j = 0; j < 4; ++j) acc[i][j] = z;

    const int aoff = (wm + fr) * 32 + ca;
    const int boff = (wn + fr) * 32 + ca;
    const int Kt = K >> 5;   // 128

    short8 ah0[4], ah1[4], bfA[4], bfB[4];

    KPRO();
    KLOOP();

    // ---- SwiGLU epilogue: even 16-frag = gate, odd = up (R7-verified) ----
    const float gsc = *gs_p;
    const float usc = *us_p;
    const int row0 = m_base + wm + ((lane >> 4) << 2);
    const int col0 = n0 + by * 128 + (wn >> 1) + fr;
#pragma unroll
    for (int mi = 0; mi < 8; ++mi)
#pragma unroll
        for (int p = 0; p < 2; ++p)
#pragma unroll
            for (int r = 0; r < 4; ++r) {
                float g = acc[mi][2 * p][r] * gsc;
                float u = acc[mi][2 * p + 1][r] * usc;
                float s = g / (1.0f + __expf(-g));   // silu
                inter[(size_t)(row0 + mi * 16 + r) * I + (col0 + p * 16)] =
                    f2bf(s * u);
            }
}

// ---------------------------------------------------------------------------
// gemm2: inter[4096 x I] @ Dw[H x I]^T * ds -> out f32. Same pipeline.
// ---------------------------------------------------------------------------
__global__ __launch_bounds__(512, 2)
void gemm2_down(const unsigned short* __restrict__ Ab,
                const unsigned short* __restrict__ Dw,
                float* __restrict__ out,
                const float* __restrict__ ds_p,
                int K, int H, int n0, int gy) {
    extern __shared__ unsigned short lds[];

    int bx, by;
    remap_block(gy, bx, by);

    const int t = threadIdx.x;
    const int lane = t & 63;
    const int wid = t >> 6;
    const int wm = (wid >> 2) * 128;
    const int wn = (wid & 3) * 64;
    const int fr = lane & 15;
    const int ca = (((lane >> 4) ^ ((fr >> 1) & 3)) << 3);

    const int m_base = bx * 256;
    const long b_row0 = (long)by * 256;

    const int colsw = (((t & 3) ^ ((t >> 3) & 3)) << 3);
    const unsigned short* pa0 = Ab + (size_t)(m_base + (t >> 2)) * K + colsw;
    const unsigned short* pa1 = pa0 + (size_t)128 * K;
    const unsigned short* pb0 = Dw + (size_t)(b_row0 + (t >> 2)) * K + colsw;
    const unsigned short* pb1 = pb0 + (size_t)128 * K;

    f32x4 acc[8][4];
    const f32x4 z = {0.0f, 0.0f, 0.0f, 0.0f};
#pragma unroll
    for (int i = 0; i < 8; ++i)
#pragma unroll
        for (int j = 0; j < 4; ++j) acc[i][j] = z;

    const int aoff = (wm + fr) * 32 + ca;
    const int boff = (wn + fr) * 32 + ca;
    const int Kt = K >> 5;   // 344

    short8 ah0[4], ah1[4], bfA[4], bfB[4];

    KPRO();
    KLOOP();

    const float dsc = *ds_p;
    const int row0 = m_base + wm + ((lane >> 4) << 2);
    const int col0 = n0 + by * 256 + wn + fr;
#pragma unroll
    for (int mi = 0; mi < 8; ++mi)
#pragma unroll
        for (int ni = 0; ni < 4; ++ni)
#pragma unroll
            for (int r = 0; r < 4; ++r)
                out[(size_t)(row0 + mi * 16 + r) * H + (col0 + ni * 16)] =
                    acc[mi][ni][r] * dsc;
}

extern "C" void kernel_launch(void* const* d_in, const int* in_sizes, int n_in,
                              void* d_out, int out_size, void* d_ws, size_t ws_size,
                              hipStream_t stream) {
    (void)in_sizes; (void)n_in; (void)out_size;
    const float* x  = (const float*)d_in[0];
    const float* gw = (const float*)d_in[1];
    const float* uw = (const float*)d_in[2];
    const float* dw = (const float*)d_in[3];
    const float* gs = (const float*)d_in[4];
    const float* us = (const float*)d_in[5];
    const float* ds = (const float*)d_in[6];
    float* out = (float*)d_out;

    const long M = 4096;    // BATCH*SEQ
    const long Kh = 4096;   // HIDDEN
    const long I = 11008;   // INTER
    const long H = 4096;

    (void)hipFuncSetAttribute(reinterpret_cast<const void*>(gemm1_swiglu),
                              hipFuncAttributeMaxDynamicSharedMemorySize, 131072);
    (void)hipFuncSetAttribute(reinterpret_cast<const void*>(gemm2_down),
                              hipFuncAttributeMaxDynamicSharedMemorySize, 131072);

    char* ws = (char*)d_ws;
    unsigned short* Xb = (unsigned short*)ws;                       // M*Kh bf16
    unsigned short* inter = (unsigned short*)(ws + M * Kh * 2);     // M*I bf16
    const size_t used = (size_t)M * Kh * 2 + (size_t)M * I * 2;     // ~124 MB
    if (ws_size < used + 2 * (size_t)256 * Kh * 2) return;
    char* wbuf = ws + used;
    const size_t avail = ws_size - used;

    // ---- x -> bf16 ----
    {
        long n4 = M * Kh / 4;
        cvt_f32_bf16<<<dim3((unsigned)((n4 + 255) / 256)), dim3(256), 0, stream>>>(
            (const fvec4*)x, (usvec4*)Xb, n4);
    }

    // ---- phase 1: interleaved gate/up convert + fused GEMM1 ----
    long mr1 = (long)(avail / ((size_t)2 * Kh * 2));   // inter cols per chunk
    mr1 = (mr1 / 128) * 128;
    if (mr1 > I) mr1 = I;
    if (mr1 < 128) mr1 = 128;
    unsigned short* Wc = (unsigned short*)wbuf;        // 2*mr1 x Kh interleaved
    for (long n0 = 0; n0 < I; n0 += mr1) {
        long rc = (I - n0 < mr1) ? (I - n0) : mr1;
        long e4 = rc * Kh / 4;
        unsigned cb = (unsigned)((e4 + 255) / 256);
        cvt2_f32_bf16_ilv<<<dim3(cb), dim3(256), 0, stream>>>(
            (const fvec4*)(gw + n0 * Kh), (const fvec4*)(uw + n0 * Kh),
            (usvec4*)Wc, e4);
        unsigned gy = (unsigned)(rc / 128);   // combined-N tiles of 256
        gemm1_swiglu<<<dim3(16, gy), dim3(512), 131072, stream>>>(
            Xb, Wc, inter, gs, us, (int)Kh, (int)I, (int)n0, (int)gy);
    }

    // ---- phase 2: down convert + GEMM2 ----
    long mr2 = (long)(avail / ((size_t)I * 2));
    mr2 = (mr2 / 256) * 256;
    if (mr2 > H) mr2 = H;
    if (mr2 < 256) mr2 = 256;
    unsigned short* Wd = (unsigned short*)wbuf;
    for (long h0 = 0; h0 < H; h0 += mr2) {
        long rc = (H - h0 < mr2) ? (H - h0) : mr2;
        long e4 = rc * I / 4;
        unsigned cb = (unsigned)((e4 + 255) / 256);
        cvt_f32_bf16<<<dim3(cb), dim3(256), 0, stream>>>(
            (const fvec4*)(dw + h0 * I), (usvec4*)Wd, e4);
        unsigned gy = (unsigned)(rc / 256);
        gemm2_down<<<dim3(16, gy), dim3(512), 131072, stream>>>(
            inter, Wd, out, ds, (int)I, (int)H, (int)h0, (int)gy);
    }
}